// Round 1
// 170.152 us; speedup vs baseline: 1.0060x; 1.0060x over previous
//
#include <hip/hip_runtime.h>
#include <stdint.h>

// ---------------------------------------------------------------------------
// PlaneEmbeddingNetwork, round 8.
// R7 baseline: 97us/dispatch, VALUBusy 65%, MfmaUtil 0, HBM 22%. VALU busy
// time (~63us) matches the known ~66us VALU work floor -> the ~34% idle is
// stall, and the only wait-generating hot-path instrs are 136 ds_bpermute
// per lane (scores 24, PV 48, h-loop quad-reduce 64 -- the latter a SERIAL
// h->DS->add->DS->add chain per c-iteration).
// This round: every cross-lane op is intra-quad (rot 1/2/3, xor 1/2) ==
// DPP quad_perm. Replace ALL ds_bpermute with v_mov_b32_dpp: 1 VALU slot,
// VALU latency, no lgkmcnt, bit-exact. Kernel becomes DS-free.
// Numerics untouched: absmax must stay exactly 0.00390625.
// ---------------------------------------------------------------------------

typedef float v2f __attribute__((ext_vector_type(2)));
typedef _Float16 v2h __attribute__((ext_vector_type(2)));

// DPP quad_perm ctrl: sel0 | sel1<<2 | sel2<<4 | sel3<<6 (out lane i <- sel[i])
#define DPP_ROT1 0x39  // [1,2,3,0]  lane t <- (t+1)&3
#define DPP_ROT2 0x4E  // [2,3,0,1]  lane t <- (t+2)&3  (== xor 2)
#define DPP_ROT3 0x93  // [3,0,1,2]  lane t <- (t+3)&3
#define DPP_XOR1 0xB1  // [1,0,3,2]  lane t <- t^1

static __device__ __forceinline__ v2f splat2(float x) { v2f r; r.x = x; r.y = x; return r; }
static __device__ __forceinline__ v2f fma2(v2f a, v2f b, v2f c) {
    return __builtin_elementwise_fma(a, b, c);
}

template<int CTRL>
static __device__ __forceinline__ float dppf(float x) {
    return __builtin_bit_cast(float,
        __builtin_amdgcn_mov_dpp(__builtin_bit_cast(int, x), CTRL, 0xF, 0xF, true));
}
template<int CTRL>
static __device__ __forceinline__ v2h dpph(v2h x) {
    return __builtin_bit_cast(v2h,
        __builtin_amdgcn_mov_dpp(__builtin_bit_cast(int, x), CTRL, 0xF, 0xF, true));
}
template<int CTRL>
static __device__ __forceinline__ v2f dpp2(v2f x) {
    v2f r; r.x = dppf<CTRL>(x.x); r.y = dppf<CTRL>(x.y); return r;
}

static __device__ __forceinline__ v2h pkh(float a, float b) {
    v2h r; r.x = (_Float16)a; r.y = (_Float16)b; return r;  // RNE casts
}
static __device__ __forceinline__ float fdot2(v2h a, v2h b, float c) {
#if __has_builtin(__builtin_amdgcn_fdot2)
    return __builtin_amdgcn_fdot2(a, b, c, false);
#else
    return fmaf((float)a.x, (float)b.x, fmaf((float)a.y, (float)b.y, c));
#endif
}
static __device__ __forceinline__ v2h ldh2(const uint32_t* p) {
    return __builtin_bit_cast(v2h, *p);
}

// scores rotation r: a{h} += q_t . k_{(t+r)&3} via DPP-rotated k
template<int CTRL>
static __device__ __forceinline__ void score_rot(const v2h* qh, const v2h* kh,
                                                 float& r0, float& r1) {
    float a0 = 0.f, a1 = 0.f;
#pragma unroll
    for (int d = 0; d < 4; ++d) {
        a0 = fdot2(qh[d],     dpph<CTRL>(kh[d]),     a0);
        a1 = fdot2(qh[4 + d], dpph<CTRL>(kh[4 + d]), a1);
    }
    r0 = a0; r1 = a1;
}

// PV rotation r: o += p[r] * v_{(t+r)&3} via DPP-rotated v
template<int CTRL>
static __device__ __forceinline__ void pv_rot(const v2f* v, float pr0, float pr1,
                                              v2f* o) {
    const v2f ps0 = splat2(pr0), ps1 = splat2(pr1);
#pragma unroll
    for (int d = 0; d < 8; ++d) {
        const v2f vr = dpp2<CTRL>(v[d]);
        o[d] = fma2(d < 4 ? ps0 : ps1, vr, o[d]);
    }
}

// ---------------------------------------------------------------------------
// Setup kernel. ws layout (4-byte units):
//  [0   .. 384): half2 wqkv[o*8+p]  = (w_in[2p][o], w_in[2p+1][o]), o in [0,48)
//  [384 .. 640): half2 w1t[c*8+p]   = (W1T[c][2p], W1T[c][2p+1]),   c in [0,32)
//                where W1T[c][d] = sum_e w_out[d*16+e] * fc_w[e*32+c]
//  [640 .. 672): float b1[c] = sum_e b_out[e]*fc_w[e*32+c] + fc_b[c]
// ---------------------------------------------------------------------------
__global__ void fold_w(const float* __restrict__ w_in,
                       const float* __restrict__ w_out,
                       const float* __restrict__ b_out,
                       const float* __restrict__ fc_w,
                       const float* __restrict__ fc_b,
                       uint32_t* __restrict__ wsu) {
    const int tid = threadIdx.x;
    if (tid < 384) {                       // region A: packed w_in
        const int o = tid >> 3, p = tid & 7;
        const v2h h = pkh(w_in[(2 * p) * 48 + o], w_in[(2 * p + 1) * 48 + o]);
        wsu[tid] = __builtin_bit_cast(uint32_t, h);
    } else if (tid < 640) {                // region B: packed W1T
        const int i = tid - 384, c = i >> 3, p = i & 7;
        float a0 = 0.f, a1 = 0.f;
#pragma unroll
        for (int e = 0; e < 16; ++e) {
            a0 = fmaf(w_out[(2 * p) * 16 + e],     fc_w[e * 32 + c], a0);
            a1 = fmaf(w_out[(2 * p + 1) * 16 + e], fc_w[e * 32 + c], a1);
        }
        wsu[tid] = __builtin_bit_cast(uint32_t, pkh(a0, a1));
    } else if (tid < 672) {                // region C: b1 (f32)
        const int c = tid - 640;
        float acc = fc_b[c];
#pragma unroll
        for (int e = 0; e < 16; ++e)
            acc = fmaf(b_out[e], fc_w[e * 32 + c], acc);
        reinterpret_cast<float*>(wsu)[640 + c] = acc;
    }
}

__launch_bounds__(256, 3)
__global__ void face_net(const float* __restrict__ node,
                         const int*   __restrict__ fids,
                         const float* __restrict__ b_in,
                         const uint32_t* __restrict__ wsu,
                         const float* __restrict__ fco_w,
                         const float* __restrict__ fco_b,
                         float* __restrict__ out, int F) {
    const int g = blockIdx.x * 256 + threadIdx.x;
    const int f = g >> 2;
    if (f >= F) return;               // whole quads exit together (face-aligned)
    const int t = g & 3;

    // ---- gather own token's embedding; convert to 8 half2 d-pairs
    const int nid = fids[g];
    const float* xp = node + (size_t)nid * 16;
    const float4 xv0 = *reinterpret_cast<const float4*>(xp);
    const float4 xv1 = *reinterpret_cast<const float4*>(xp + 4);
    const float4 xv2 = *reinterpret_cast<const float4*>(xp + 8);
    const float4 xv3 = *reinterpret_cast<const float4*>(xp + 12);
    v2h xh[8];
    xh[0] = pkh(xv0.x, xv0.y); xh[1] = pkh(xv0.z, xv0.w);
    xh[2] = pkh(xv1.x, xv1.y); xh[3] = pkh(xv1.z, xv1.w);
    xh[4] = pkh(xv2.x, xv2.y); xh[5] = pkh(xv2.z, xv2.w);
    xh[6] = pkh(xv3.x, xv3.y); xh[7] = pkh(xv3.z, xv3.w);

    // ---- qkv projection via fdot2 (f32 accumulators, f16 inputs).
    //      k-bias dropped (softmax row-constant).
    float qa[16], ka[16], va[16];
#pragma unroll
    for (int o = 0; o < 16; ++o) {
        float aq = b_in[o], ak = 0.f, av = b_in[32 + o];
        const uint32_t* wq = wsu + o * 8;          // uniform -> s_load
        const uint32_t* wk = wsu + (16 + o) * 8;
        const uint32_t* wv = wsu + (32 + o) * 8;
#pragma unroll
        for (int p = 0; p < 8; ++p) {
            aq = fdot2(xh[p], ldh2(wq + p), aq);
            ak = fdot2(xh[p], ldh2(wk + p), ak);
            av = fdot2(xh[p], ldh2(wv + p), av);
        }
        qa[o] = aq; ka[o] = ak; va[o] = av;
    }

    // q,k as half2 pairs; v stays f32 for PV.
    v2h qh[8], kh[8];
    v2f v[8];
#pragma unroll
    for (int i = 0; i < 8; ++i) {
        qh[i] = pkh(qa[2 * i], qa[2 * i + 1]);
        kh[i] = pkh(ka[2 * i], ka[2 * i + 1]);
        v[i].x = va[2 * i]; v[i].y = va[2 * i + 1];
    }

    // ---- scores: p{h}[r] = q_t . k_{(t+r)%4}; k rotated by DPP quad_perm.
    //      Head0 = pairs 0..3, head1 = pairs 4..7.
    float p0[4], p1[4];
    {
        float a0 = 0.f, a1 = 0.f;
#pragma unroll
        for (int d = 0; d < 4; ++d) {
            a0 = fdot2(qh[d], kh[d], a0);
            a1 = fdot2(qh[4 + d], kh[4 + d], a1);
        }
        p0[0] = a0; p1[0] = a1;
    }
    score_rot<DPP_ROT1>(qh, kh, p0[1], p1[1]);
    score_rot<DPP_ROT2>(qh, kh, p0[2], p1[2]);
    score_rot<DPP_ROT3>(qh, kh, p0[3], p1[3]);

    {   // softmax, no max-subtract (|score*scale| <~ 20 << exp2 range)
        const float C = 0.51006974841f;   // (1/sqrt(8)) * log2(e)
        float s0 = 0.f, s1 = 0.f;
#pragma unroll
        for (int j = 0; j < 4; ++j) {
            p0[j] = __builtin_amdgcn_exp2f(p0[j] * C); s0 += p0[j];
            p1[j] = __builtin_amdgcn_exp2f(p1[j] * C); s1 += p1[j];
        }
        const float r0 = __builtin_amdgcn_rcpf(s0);
        const float r1 = __builtin_amdgcn_rcpf(s1);
#pragma unroll
        for (int j = 0; j < 4; ++j) { p0[j] *= r0; p1[j] *= r1; }
    }

    // ---- PV (f32): o_t = sum_r p[r] * v_{(t+r)%4}, v rotated by DPP
    v2f o[8];
#pragma unroll
    for (int d = 0; d < 4; ++d) {
        o[d]     = splat2(p0[0]) * v[d];
        o[4 + d] = splat2(p1[0]) * v[4 + d];
    }
    pv_rot<DPP_ROT1>(v, p0[1], p1[1], o);
    pv_rot<DPP_ROT2>(v, p0[2], p1[2], o);
    pv_rot<DPP_ROT3>(v, p0[3], p1[3], o);

    // o -> half2 pairs for the h-loop dots
    v2h oh[8];
#pragma unroll
    for (int i = 0; i < 8; ++i) oh[i] = pkh(o[i].x, o[i].y);

    // ---- fused: h_t[c] = relu(o_t . W1T[c] + b1[c]) via fdot2;
    //      pooled_c = quadsum/4 (DPP butterfly); lane accumulates its 8 cols.
    const uint32_t* w1t = wsu + 384;
    const float* b1 = reinterpret_cast<const float*>(wsu) + 640;
    const int t8 = t * 8;
    const float4 ob0 = *reinterpret_cast<const float4*>(fco_b + t8);
    const float4 ob1 = *reinterpret_cast<const float4*>(fco_b + t8 + 4);
    v2f oacc[4];
    oacc[0].x = ob0.x; oacc[0].y = ob0.y; oacc[1].x = ob0.z; oacc[1].y = ob0.w;
    oacc[2].x = ob1.x; oacc[2].y = ob1.y; oacc[3].x = ob1.z; oacc[3].y = ob1.w;
    const float* fwt = fco_w + t8;   // lane-varying base

#pragma unroll 4
    for (int c = 0; c < 32; ++c) {
        const uint32_t* wr = w1t + c * 8;          // uniform -> s_load
        float a = b1[c];
#pragma unroll
        for (int p = 0; p < 8; ++p) a = fdot2(oh[p], ldh2(wr + p), a);
        const float h = fmaxf(a, 0.f);
        float s = h + dppf<DPP_XOR1>(h);           // + lane^1
        s = s + dppf<DPP_ROT2>(s);                 // + lane^2 (quad-uniform)
        const float pc = s * 0.25f;
        const v2f ps = splat2(pc);
        // lane-varying columns of fco_w: 4KB table, L1-resident
        const float4 f0 = *reinterpret_cast<const float4*>(fwt + c * 32);
        const float4 f1 = *reinterpret_cast<const float4*>(fwt + c * 32 + 4);
        v2f w01; w01.x = f0.x; w01.y = f0.y;
        v2f w23; w23.x = f0.z; w23.y = f0.w;
        v2f w45; w45.x = f1.x; w45.y = f1.y;
        v2f w67; w67.x = f1.z; w67.y = f1.w;
        oacc[0] = fma2(ps, w01, oacc[0]);
        oacc[1] = fma2(ps, w23, oacc[1]);
        oacc[2] = fma2(ps, w45, oacc[2]);
        oacc[3] = fma2(ps, w67, oacc[3]);
    }

    // ---- store: 16B/lane, contiguous across the quad and wave
    float* op = out + (size_t)f * 32 + t8;
    *reinterpret_cast<float4*>(op)     = make_float4(oacc[0].x, oacc[0].y, oacc[1].x, oacc[1].y);
    *reinterpret_cast<float4*>(op + 4) = make_float4(oacc[2].x, oacc[2].y, oacc[3].x, oacc[3].y);
}

extern "C" void kernel_launch(void* const* d_in, const int* in_sizes, int n_in,
                              void* d_out, int out_size, void* d_ws, size_t ws_size,
                              hipStream_t stream) {
    const float* node  = (const float*)d_in[0];
    const int*   fids  = (const int*)  d_in[1];
    const float* w_in  = (const float*)d_in[2];
    const float* b_in  = (const float*)d_in[3];
    const float* w_out = (const float*)d_in[4];
    const float* b_out = (const float*)d_in[5];
    const float* fc_w  = (const float*)d_in[6];
    const float* fc_b  = (const float*)d_in[7];
    const float* fco_w = (const float*)d_in[8];
    const float* fco_b = (const float*)d_in[9];
    float* out = (float*)d_out;
    uint32_t* wsu = (uint32_t*)d_ws;
    const int F = in_sizes[1] / 4;

    hipLaunchKernelGGL(fold_w, dim3(1), dim3(672), 0, stream,
                       w_in, w_out, b_out, fc_w, fc_b, wsu);
    const int threads = F * 4;
    const int blocks = (threads + 255) / 256;
    hipLaunchKernelGGL(face_net, dim3(blocks), dim3(256), 0, stream,
                       node, fids, b_in, wsu, fco_w, fco_b, out, F);
}